// Round 7
// baseline (378.160 us; speedup 1.0000x reference)
//
#include <hip/hip_runtime.h>
#include <hip/hip_cooperative_groups.h>

namespace cg = cooperative_groups;

// EquivariantGraphConvCheap: N=50000, E=500000, H=128.
// R11: single cooperative mega-kernel. Fused phase pinned at the byte-
//      proportional ~2.3 TB/s ceiling (5x reproduced; all latency/occupancy
//      knobs null) -- body unchanged. Aux overlap (R10) was null, so the
//      ~120us of aux overhead beyond the byte model is launch/gap/ramp:
//      fold memset+prep+scan+bin+fused into ONE cooperative launch with 5
//      grid.sync()s and a dynamic atomic tile counter for the fused phase
//      (1563 tiles over ~1024 persistent blocks; static striding would
//      leave a 2x straggler tail). Fallback: R10 multi-kernel path.

typedef short bfrag __attribute__((ext_vector_type(8)));   // 8 bf16 = 4 VGPR
typedef float cfrag __attribute__((ext_vector_type(16)));  // 32x32 C/D tile
typedef float f4v  __attribute__((ext_vector_type(4)));    // for NT load

__device__ __forceinline__ short f2bf(float f) {
    unsigned u = __builtin_bit_cast(unsigned, f);
    u += 0x7fff + ((u >> 16) & 1);          // RNE
    return (short)(u >> 16);
}
__device__ __forceinline__ float bf2f(short s) {
    unsigned u = ((unsigned)(unsigned short)s) << 16;
    return __builtin_bit_cast(float, u);
}
__device__ __forceinline__ bfrag pack8(float4 lo, float4 hi) {
    bfrag r;
    r[0] = f2bf(lo.x); r[1] = f2bf(lo.y); r[2] = f2bf(lo.z); r[3] = f2bf(lo.w);
    r[4] = f2bf(hi.x); r[5] = f2bf(hi.y); r[6] = f2bf(hi.z); r[7] = f2bf(hi.w);
    return r;
}
__device__ __forceinline__ bfrag pack8v(f4v lo, f4v hi) {
    bfrag r;
    r[0] = f2bf(lo[0]); r[1] = f2bf(lo[1]); r[2] = f2bf(lo[2]); r[3] = f2bf(lo[3]);
    r[4] = f2bf(hi[0]); r[5] = f2bf(hi[1]); r[6] = f2bf(hi[2]); r[7] = f2bf(hi[3]);
    return r;
}

// ---------- fused tile body (R6 geometry, 5x byte-verified) ----------
// 32 nodes/tile, 4 waves. Phase A: wave w aggregates nodes m=w*8..w*8+7
// (fp32 acc, RNE->bf16) into swizzled LDS: byte = m*1024 + ch*256 +
// ((slot*16)^((m&15)<<4)). Phase B: wave = channel c, mfma 32x32x16:
// D[32x128] = Xroot@Wroot^T + Agg@Wrel^T (+bias c==0).
// C/D: col=lane&31, row=(reg&3)+8*(reg>>2)+4*(lane>>5) [m74/m101].
template<int XBF>
__device__ __forceinline__ void fused_tile_body(
    const float* __restrict__ x, const short* __restrict__ xbf,
    const int* __restrict__ offsets, const int* __restrict__ bins,
    float* __restrict__ out, const short* __restrict__ wbf,
    const float* __restrict__ b_s, int Nn, int n0, short* atile,
    int tid, int wid, int lane)
{
    const int cl   = lane >> 4;
    const int slot = lane & 15;
    #pragma unroll 1
    for (int i = 0; i < 8; i++) {
        const int m = wid * 8 + i;
        const int n = n0 + m;
        float acc[8] = {0, 0, 0, 0, 0, 0, 0, 0};
        if (n < Nn) {
            const int beg = offsets[n], end = offsets[n + 1];
            int e = beg;
            if (XBF) {
                for (; e + 8 <= end; e += 8) {
                    int cc[8];
                    #pragma unroll
                    for (int q = 0; q < 8; q++) cc[q] = bins[e + q];
                    bfrag v[8];
                    #pragma unroll
                    for (int q = 0; q < 8; q++)
                        v[q] = *(const bfrag*)(xbf + (size_t)cc[q] * 512 + lane * 8);
                    #pragma unroll
                    for (int j = 0; j < 8; j++)
                        acc[j] += ((bf2f(v[0][j]) + bf2f(v[1][j])) +
                                   (bf2f(v[2][j]) + bf2f(v[3][j]))) +
                                  ((bf2f(v[4][j]) + bf2f(v[5][j])) +
                                   (bf2f(v[6][j]) + bf2f(v[7][j])));
                }
                for (; e + 4 <= end; e += 4) {
                    int c4[4];
                    #pragma unroll
                    for (int q = 0; q < 4; q++) c4[q] = bins[e + q];
                    bfrag v[4];
                    #pragma unroll
                    for (int q = 0; q < 4; q++)
                        v[q] = *(const bfrag*)(xbf + (size_t)c4[q] * 512 + lane * 8);
                    #pragma unroll
                    for (int j = 0; j < 8; j++)
                        acc[j] += (bf2f(v[0][j]) + bf2f(v[1][j])) +
                                  (bf2f(v[2][j]) + bf2f(v[3][j]));
                }
                for (; e < end; e++) {
                    int cc1 = bins[e];
                    bfrag v = *(const bfrag*)(xbf + (size_t)cc1 * 512 + lane * 8);
                    #pragma unroll
                    for (int j = 0; j < 8; j++) acc[j] += bf2f(v[j]);
                }
            } else {
                for (; e < end; e++) {
                    int cc1 = bins[e];
                    float4 l = *(const float4*)(x + (size_t)cc1 * 512 + lane * 8);
                    float4 h = *(const float4*)(x + (size_t)cc1 * 512 + lane * 8 + 4);
                    acc[0] += l.x; acc[1] += l.y; acc[2] += l.z; acc[3] += l.w;
                    acc[4] += h.x; acc[5] += h.y; acc[6] += h.z; acc[7] += h.w;
                }
            }
        }
        const int boff = m * 1024 + cl * 256 + ((slot * 16) ^ ((m & 15) << 4));
        *(bfrag*)((char*)atile + boff) =
            pack8(make_float4(acc[0], acc[1], acc[2], acc[3]),
                  make_float4(acc[4], acc[5], acc[6], acc[7]));
    }

    const int c   = wid;
    const int l31 = lane & 31;
    const int kg  = lane >> 5;
    int mA = n0 + l31; if (mA >= Nn) mA = Nn - 1;
    const size_t arow = ((size_t)mA * 4 + c) * 128;
    bfrag a0[8];
    #pragma unroll
    for (int ks = 0; ks < 8; ks++) {
        const int k0 = ks * 16 + kg * 8;
        if (XBF) {
            a0[ks] = *(const bfrag*)(xbf + arow + k0);
        } else {
            float4 lo = *(const float4*)(x + arow + k0);
            float4 hi = *(const float4*)(x + arow + k0 + 4);
            a0[ks] = pack8(lo, hi);
        }
    }

    __syncthreads();

    const short* wroot = wbf + ((c == 0) ? 0 : 2) * 16384;
    const short* wrel  = wbf + ((c == 0) ? 1 : 3) * 16384;

    cfrag acc4[4];
    #pragma unroll
    for (int t = 0; t < 4; t++)
        #pragma unroll
        for (int r = 0; r < 16; r++) acc4[t][r] = 0.f;

    __builtin_amdgcn_s_setprio(1);
    #pragma unroll
    for (int ks = 0; ks < 8; ks++) {
        const int k0 = ks * 16 + kg * 8;
        const int rboff = l31 * 1024 + c * 256 + ((k0 * 2) ^ ((l31 & 15) << 4));
        bfrag a1 = *(const bfrag*)((const char*)atile + rboff);
        #pragma unroll
        for (int t = 0; t < 4; t++) {
            bfrag b0 = *(const bfrag*)(wroot + (size_t)(t * 32 + l31) * 128 + k0);
            acc4[t] = __builtin_amdgcn_mfma_f32_32x32x16_bf16(a0[ks], b0, acc4[t], 0, 0, 0);
            bfrag b1 = *(const bfrag*)(wrel + (size_t)(t * 32 + l31) * 128 + k0);
            acc4[t] = __builtin_amdgcn_mfma_f32_32x32x16_bf16(a1, b1, acc4[t], 0, 0, 0);
        }
    }
    __builtin_amdgcn_s_setprio(0);

    float bv[4] = {0.f, 0.f, 0.f, 0.f};
    if (c == 0) {
        #pragma unroll
        for (int t = 0; t < 4; t++) bv[t] = b_s[t * 32 + l31];
    }

    #pragma unroll
    for (int t = 0; t < 4; t++) {
        #pragma unroll
        for (int r = 0; r < 16; r++) {
            int row = (r & 3) + 8 * (r >> 2) + 4 * kg;
            int node = n0 + row;
            if (node < Nn)
                __builtin_nontemporal_store(
                    acc4[t][r] + bv[t],
                    out + ((size_t)node * 4 + c) * 128 + t * 32 + l31);
        }
    }
}

// ---------- single cooperative kernel: all phases ----------
template<int XBF>
__global__ __launch_bounds__(256) void coop_all(
    const float* __restrict__ x, short* __restrict__ xbf,
    const int* __restrict__ ei, int* __restrict__ counts,
    int* __restrict__ offsets, int* __restrict__ cursor,
    int* __restrict__ bins, int* __restrict__ blocksums,
    int* __restrict__ tile_ctr,
    float* __restrict__ out, short* __restrict__ wbf,
    const float* __restrict__ w0, const float* __restrict__ w1,
    const float* __restrict__ w2, const float* __restrict__ w3,
    const float* __restrict__ b_s, int N, int E, long long total8)
{
    __shared__ short atile[32 * 512];
    __shared__ int tsel;
    int* ip = (int*)atile;               // scan scratch overlays atile
    cg::grid_group grid = cg::this_grid();
    const int tid = threadIdx.x, lane = tid & 63, wid = tid >> 6;
    const long long gstride = (long long)gridDim.x * 256;
    const long long gtid = (long long)blockIdx.x * 256 + tid;

    // ---- phase 0: zero counts | conv_w | conv_x | zero tile counter ----
    if (gtid == 0) *tile_ctr = 0;
    for (long long i = gtid; i < N; i += gstride) counts[i] = 0;
    for (long long i = gtid; i < 8192; i += gstride) {
        int j = (int)i * 8;
        int m = j >> 14, off = j & 16383;
        const float* src = (m == 0) ? w0 : (m == 1) ? w1 : (m == 2) ? w2 : w3;
        float4 lo = *(const float4*)(src + off);
        float4 hi = *(const float4*)(src + off + 4);
        *(bfrag*)(wbf + j) = pack8(lo, hi);
    }
    if (XBF) {
        for (long long i = gtid; i < total8; i += gstride) {
            f4v lo = __builtin_nontemporal_load((const f4v*)(x + i * 8));
            f4v hi = __builtin_nontemporal_load((const f4v*)(x + i * 8 + 4));
            *(bfrag*)(xbf + i * 8) = pack8v(lo, hi);
        }
    }
    grid.sync();

    // ---- phase 1: histogram of edge rows ----
    for (long long e = gtid; e < E; e += gstride)
        atomicAdd(&counts[ei[e]], 1);
    grid.sync();

    // ---- phase 2: local exclusive scan per 256-chunk ----
    const int nchunks = (N + 255) >> 8;          // requires N <= 65536
    for (int ch = blockIdx.x; ch < nchunks; ch += gridDim.x) {
        int i = ch * 256 + tid;
        int v = (i < N) ? counts[i] : 0;
        int incl = v;
        #pragma unroll
        for (int off = 1; off < 64; off <<= 1) {
            int t = __shfl_up(incl, off, 64);
            if (lane >= off) incl += t;
        }
        if (lane == 63) ip[wid] = incl;
        __syncthreads();
        if (tid == 0) {
            int s = 0;
            #pragma unroll
            for (int k = 0; k < 4; k++) { int t = ip[k]; ip[k] = s; s += t; }
        }
        __syncthreads();
        int excl = incl - v + ip[wid];
        if (i < N) offsets[i] = excl;
        if (tid == 255) blocksums[ch] = excl + v;
        __syncthreads();
    }
    grid.sync();

    // ---- phase 3: redundant in-LDS scan of blocksums; absolutize ----
    {
        int v = (tid < nchunks) ? blocksums[tid] : 0;
        int incl = v;
        #pragma unroll
        for (int off = 1; off < 64; off <<= 1) {
            int t = __shfl_up(incl, off, 64);
            if (lane >= off) incl += t;
        }
        if (lane == 63) ip[wid] = incl;
        __syncthreads();
        if (tid == 0) {
            int s = 0;
            #pragma unroll
            for (int k = 0; k < 4; k++) { int t = ip[k]; ip[k] = s; s += t; }
        }
        __syncthreads();
        int pref = incl - v + ip[wid];           // exclusive prefix
        __syncthreads();
        ip[8 + tid] = pref;
        __syncthreads();
        for (int ch = blockIdx.x; ch < nchunks; ch += gridDim.x) {
            int base = ip[8 + ch];
            int i = ch * 256 + tid;
            if (i < N) { int vv = offsets[i] + base; offsets[i] = vv; cursor[i] = vv; }
        }
        if (blockIdx.x == 0 && tid == 0) offsets[N] = E;
    }
    grid.sync();

    // ---- phase 4: bin (counting-sort scatter) ----
    for (long long e = gtid; e < E; e += gstride) {
        int row = ei[e], col = ei[E + e];
        int pos = atomicAdd(&cursor[row], 1);
        bins[pos] = col;
    }
    grid.sync();

    // ---- phase 5: fused agg+MFMA, dynamic tile grab ----
    const int ntiles = (N + 31) >> 5;
    for (;;) {
        __syncthreads();                          // atile/tsel from prev iter done
        if (tid == 0) tsel = atomicAdd(tile_ctr, 1);
        __syncthreads();
        int t = tsel;
        if (t >= ntiles) break;                   // uniform per block
        fused_tile_body<XBF>(x, xbf, offsets, bins, out, wbf, b_s,
                             N, t * 32, atile, tid, wid, lane);
    }
}

// ---------- fallback path (R10, proven 377.8us) ----------
__global__ __launch_bounds__(256) void prep0_kernel(
    const float* __restrict__ w0, const float* __restrict__ w1,
    const float* __restrict__ w2, const float* __restrict__ w3,
    short* __restrict__ wbf,
    const int* __restrict__ ei, int* __restrict__ counts, int E)
{
    int b = blockIdx.x;
    if (b < 32) {
        int i = b * 256 + threadIdx.x;
        int j = i * 8;
        int m = j >> 14, off = j & 16383;
        const float* src = (m == 0) ? w0 : (m == 1) ? w1 : (m == 2) ? w2 : w3;
        float4 lo = *(const float4*)(src + off);
        float4 hi = *(const float4*)(src + off + 4);
        *(bfrag*)(wbf + j) = pack8(lo, hi);
    } else {
        int e = (b - 32) * 256 + threadIdx.x;
        if (e < E) atomicAdd(&counts[ei[e]], 1);
    }
}

__global__ __launch_bounds__(1024) void scan_local_kernel(
    const int* __restrict__ counts, int* __restrict__ offsets,
    int* __restrict__ cursor, int* __restrict__ blocksums, int N)
{
    __shared__ int wsum[16];
    const int tid = threadIdx.x, lane = tid & 63, wid = tid >> 6;
    int i = blockIdx.x * 1024 + tid;
    int v = (i < N) ? counts[i] : 0;
    int incl = v;
    #pragma unroll
    for (int off = 1; off < 64; off <<= 1) {
        int t = __shfl_up(incl, off, 64);
        if (lane >= off) incl += t;
    }
    if (lane == 63) wsum[wid] = incl;
    __syncthreads();
    if (wid == 0) {
        int ws = (lane < 16) ? wsum[lane] : 0;
        int wincl = ws;
        #pragma unroll
        for (int off = 1; off < 16; off <<= 1) {
            int t = __shfl_up(wincl, off, 64);
            if (lane >= off) wincl += t;
        }
        if (lane < 16) wsum[lane] = wincl - ws;
    }
    __syncthreads();
    int excl = incl - v + wsum[wid];
    if (i < N) { offsets[i] = excl; cursor[i] = excl; }
    if (tid == 1023) blocksums[blockIdx.x] = excl + v;
}

__global__ __launch_bounds__(256) void mega_kernel(
    const int* __restrict__ ei, int* __restrict__ cursor,
    int* __restrict__ bins, int E,
    int* __restrict__ offsets, const int* __restrict__ blocksums,
    int nb, int N,
    const float* __restrict__ x, short* __restrict__ xbf, long long total8,
    int nbin, int nfix)
{
    int b = blockIdx.x;
    if (b < nbin + nfix) {
        __shared__ int pref[64];
        if (threadIdx.x < 64) {
            int lane = threadIdx.x;
            int v = (lane < nb) ? blocksums[lane] : 0;
            int incl = v;
            #pragma unroll
            for (int off = 1; off < 64; off <<= 1) {
                int t = __shfl_up(incl, off, 64);
                if (lane >= off) incl += t;
            }
            pref[lane] = incl - v;
        }
        __syncthreads();
        if (b < nbin) {
            int e = b * 256 + threadIdx.x;
            if (e < E) {
                int row = ei[e], col = ei[E + e];
                int pos = atomicAdd(&cursor[row], 1) + pref[row >> 10];
                bins[pos] = col;
            }
        } else {
            int i = (b - nbin) * 256 + threadIdx.x;
            if (i < N) offsets[i] += pref[i >> 10];
            else if (i == N) offsets[i] = E;
        }
    } else {
        long long i = (long long)(b - nbin - nfix) * 256 + threadIdx.x;
        if (i >= total8) return;
        f4v lo = __builtin_nontemporal_load((const f4v*)(x + i * 8));
        f4v hi = __builtin_nontemporal_load((const f4v*)(x + i * 8 + 4));
        *(bfrag*)(xbf + i * 8) = pack8v(lo, hi);
    }
}

template<int XBF>
__global__ __launch_bounds__(256) void fused_agg_mfma(
    const float* __restrict__ x, const short* __restrict__ xbf,
    const int* __restrict__ offsets, const int* __restrict__ bins,
    float* __restrict__ out, const short* __restrict__ wbf,
    const float* __restrict__ b_s, int Nn)
{
    __shared__ short atile[32 * 512];
    fused_tile_body<XBF>(x, xbf, offsets, bins, out, wbf, b_s,
                         Nn, blockIdx.x * 32, atile,
                         threadIdx.x, threadIdx.x >> 6, threadIdx.x & 63);
}

extern "C" void kernel_launch(void* const* d_in, const int* in_sizes, int n_in,
                              void* d_out, int out_size, void* d_ws, size_t ws_size,
                              hipStream_t stream) {
    const float* x        = (const float*)d_in[0];
    const int*   ei       = (const int*)d_in[1];
    const float* W_s_rel  = (const float*)d_in[2];
    const float* W_s_root = (const float*)d_in[3];
    const float* b_s_root = (const float*)d_in[4];
    const float* W_v_rel  = (const float*)d_in[5];
    const float* W_v_root = (const float*)d_in[6];
    float* out = (float*)d_out;

    int N = in_sizes[0] / 512;   // 50000
    int E = in_sizes[1] / 2;     // 500000

    // ws layout: wbf[65536 shorts] | (xbf[N*512 shorts] if it fits) | ints:
    //   counts[N] offsets[N+1] cursor[N] bins[E] blocksums[256] tile_ctr[1]
    size_t ints_bytes = ((size_t)(3 * N + 1) + E + 257) * sizeof(int);
    size_t wbf_bytes  = 65536 * sizeof(short);
    size_t xbf_bytes  = (size_t)N * 512 * sizeof(short);
    bool use_bf = (ws_size >= wbf_bytes + xbf_bytes + ints_bytes);

    short* wbf = (short*)d_ws;
    short* xbf = use_bf ? (wbf + 65536) : nullptr;
    int* counts = use_bf ? (int*)(wbf + 65536 + (size_t)N * 512)
                         : (int*)(wbf + 65536);
    int* offsets   = counts + N;
    int* cursor    = offsets + N + 1;
    int* bins      = cursor + N;
    int* blocksums = bins + E;
    int* tile_ctr  = blocksums + 256;

    long long total8 = use_bf ? (long long)N * 64 : 0;

    // ---- cooperative capability + grid size (cached) ----
    static int coop_grid = -2;
    if (coop_grid == -2) {
        int dev = 0;
        hipGetDevice(&dev);
        int coop = 0;
        hipDeviceGetAttribute(&coop, hipDeviceAttributeCooperativeLaunch, dev);
        if (coop) {
            hipDeviceProp_t prop{};
            hipGetDeviceProperties(&prop, dev);
            int nbpc = 0;
            hipOccupancyMaxActiveBlocksPerMultiprocessor(&nbpc, coop_all<1>, 256, 0);
            coop_grid = (nbpc > 0 && prop.multiProcessorCount > 0)
                      ? nbpc * prop.multiProcessorCount : -1;
        } else {
            coop_grid = -1;
        }
    }

    if (coop_grid > 0 && N <= 65536) {
        void* kf = use_bf ? (void*)&coop_all<1> : (void*)&coop_all<0>;
        void* args[] = {
            (void*)&x, (void*)&xbf, (void*)&ei, (void*)&counts,
            (void*)&offsets, (void*)&cursor, (void*)&bins, (void*)&blocksums,
            (void*)&tile_ctr, (void*)&out, (void*)&wbf,
            (void*)&W_s_root, (void*)&W_s_rel, (void*)&W_v_root, (void*)&W_v_rel,
            (void*)&b_s_root, (void*)&N, (void*)&E, (void*)&total8
        };
        hipLaunchCooperativeKernel(kf, dim3(coop_grid), dim3(256), args, 0, stream);
        return;
    }

    // ---- fallback: R10 multi-kernel path ----
    int nb = (N + 1023) / 1024;
    int nconv = use_bf ? (int)((total8 + 255) / 256) : 0;
    int nbin  = (E + 255) / 256;
    int nfix  = (N + 1 + 255) / 256;

    hipMemsetAsync(counts, 0, (size_t)N * sizeof(int), stream);
    prep0_kernel<<<32 + nbin, 256, 0, stream>>>(
        W_s_root, W_s_rel, W_v_root, W_v_rel, wbf, ei, counts, E);
    scan_local_kernel<<<nb, 1024, 0, stream>>>(counts, offsets, cursor, blocksums, N);
    mega_kernel<<<nbin + nfix + nconv, 256, 0, stream>>>(
        ei, cursor, bins, E, offsets, blocksums, nb, N,
        x, xbf, total8, nbin, nfix);

    if (use_bf) {
        fused_agg_mfma<1><<<(N + 31) / 32, 256, 0, stream>>>(
            x, xbf, offsets, bins, out, wbf, b_s_root, N);
    } else {
        fused_agg_mfma<0><<<(N + 31) / 32, 256, 0, stream>>>(
            x, nullptr, offsets, bins, out, wbf, b_s_root, N);
    }
}

// Round 8
// 376.601 us; speedup vs baseline: 1.0041x; 1.0041x over previous
//
#include <hip/hip_runtime.h>

// EquivariantGraphConvCheap: N=50000, E=500000, H=128.
// R12: best-of arrangement. R11 proved launch gaps are small and the coop
//      mega-kernel strangles streaming phases (140 VGPR everywhere, occ 11%).
//      R11 counters also showed FETCH counts L2-miss/fabric traffic: fused's
//      257MB vs 53MB footprint = random gathers miss the 4MB/XCD L2; the
//      2.3 TB/s ceiling is fabric BW. Fused untouched (6x reproduced).
//      Aux: conv_x moved INTO prep (overlaps hist, off the serial tail);
//      binfix = bin + offset-absolutize with in-LDS blocksums prefix.
//      memset -> prep -> scan_local -> binfix -> fused (5 enqueues).

typedef short bfrag __attribute__((ext_vector_type(8)));   // 8 bf16 = 4 VGPR
typedef float cfrag __attribute__((ext_vector_type(16)));  // 32x32 C/D tile
typedef float f4v  __attribute__((ext_vector_type(4)));    // for NT load

__device__ __forceinline__ short f2bf(float f) {
    unsigned u = __builtin_bit_cast(unsigned, f);
    u += 0x7fff + ((u >> 16) & 1);          // RNE
    return (short)(u >> 16);
}
__device__ __forceinline__ float bf2f(short s) {
    unsigned u = ((unsigned)(unsigned short)s) << 16;
    return __builtin_bit_cast(float, u);
}
__device__ __forceinline__ bfrag pack8(float4 lo, float4 hi) {
    bfrag r;
    r[0] = f2bf(lo.x); r[1] = f2bf(lo.y); r[2] = f2bf(lo.z); r[3] = f2bf(lo.w);
    r[4] = f2bf(hi.x); r[5] = f2bf(hi.y); r[6] = f2bf(hi.z); r[7] = f2bf(hi.w);
    return r;
}
__device__ __forceinline__ bfrag pack8v(f4v lo, f4v hi) {
    bfrag r;
    r[0] = f2bf(lo[0]); r[1] = f2bf(lo[1]); r[2] = f2bf(lo[2]); r[3] = f2bf(lo[3]);
    r[4] = f2bf(hi[0]); r[5] = f2bf(hi[1]); r[6] = f2bf(hi[2]); r[7] = f2bf(hi[3]);
    return r;
}

// ---------- prep: conv_x | conv_w | hist (one launch) ----------
// blocks [0, convB)        : x fp32 -> bf16 (NT loads; x read exactly once)
// blocks [convB, convB+32) : weights fp32 -> bf16, wbf layout
//                            [Ws_root | Ws_rel | Wv_root | Wv_rel] 128x128 [o][h]
// blocks [convB+32, ...)   : histogram of edge rows (fire-and-forget atomics)
__global__ __launch_bounds__(256) void prep_kernel(
    const float* __restrict__ x, short* __restrict__ xbf, long long total8,
    const float* __restrict__ w0, const float* __restrict__ w1,
    const float* __restrict__ w2, const float* __restrict__ w3,
    short* __restrict__ wbf,
    const int* __restrict__ ei, int* __restrict__ counts, int E,
    int convB)
{
    int b = blockIdx.x;
    if (b < convB) {
        long long i = (long long)b * 256 + threadIdx.x;
        if (i >= total8) return;
        f4v lo = __builtin_nontemporal_load((const f4v*)(x + i * 8));
        f4v hi = __builtin_nontemporal_load((const f4v*)(x + i * 8 + 4));
        *(bfrag*)(xbf + i * 8) = pack8v(lo, hi);
    } else if (b < convB + 32) {
        int i = (b - convB) * 256 + threadIdx.x;   // 0..8191
        int j = i * 8;
        int m = j >> 14, off = j & 16383;
        const float* src = (m == 0) ? w0 : (m == 1) ? w1 : (m == 2) ? w2 : w3;
        float4 lo = *(const float4*)(src + off);
        float4 hi = *(const float4*)(src + off + 4);
        *(bfrag*)(wbf + j) = pack8(lo, hi);
    } else {
        int e = (b - convB - 32) * 256 + threadIdx.x;
        if (e < E) atomicAdd(&counts[ei[e]], 1);
    }
}

// ---------- per-block local scan ----------
// offsets[i], cursor[i] = block-LOCAL exclusive prefix; blocksums[b] = total.
__global__ __launch_bounds__(1024) void scan_local_kernel(
    const int* __restrict__ counts, int* __restrict__ offsets,
    int* __restrict__ cursor, int* __restrict__ blocksums, int N)
{
    __shared__ int wsum[16];
    const int tid = threadIdx.x, lane = tid & 63, wid = tid >> 6;
    int i = blockIdx.x * 1024 + tid;
    int v = (i < N) ? counts[i] : 0;
    int incl = v;
    #pragma unroll
    for (int off = 1; off < 64; off <<= 1) {
        int t = __shfl_up(incl, off, 64);
        if (lane >= off) incl += t;
    }
    if (lane == 63) wsum[wid] = incl;
    __syncthreads();
    if (wid == 0) {
        int ws = (lane < 16) ? wsum[lane] : 0;
        int wincl = ws;
        #pragma unroll
        for (int off = 1; off < 16; off <<= 1) {
            int t = __shfl_up(wincl, off, 64);
            if (lane >= off) wincl += t;
        }
        if (lane < 16) wsum[lane] = wincl - ws;
    }
    __syncthreads();
    int excl = incl - v + wsum[wid];
    if (i < N) { offsets[i] = excl; cursor[i] = excl; }
    if (tid == 1023) blocksums[blockIdx.x] = excl + v;
}

// ---------- binfix = bin | offset-absolutize ----------
// All blocks first scan the nb(<=64)-entry blocksums in-LDS (1 wave).
// bin:  pos = atomicAdd(&cursor_local[row],1) + pref[row>>10]; bins[pos]=col
// fix:  offsets[i] += pref[i>>10]; offsets[N] = E
__global__ __launch_bounds__(256) void binfix_kernel(
    const int* __restrict__ ei, int* __restrict__ cursor,
    int* __restrict__ bins, int E,
    int* __restrict__ offsets, const int* __restrict__ blocksums,
    int nb, int N, int nbin)
{
    __shared__ int pref[64];
    if (threadIdx.x < 64) {
        int lane = threadIdx.x;
        int v = (lane < nb) ? blocksums[lane] : 0;   // nb <= 64 (N <= 64K)
        int incl = v;
        #pragma unroll
        for (int off = 1; off < 64; off <<= 1) {
            int t = __shfl_up(incl, off, 64);
            if (lane >= off) incl += t;
        }
        pref[lane] = incl - v;
    }
    __syncthreads();
    int b = blockIdx.x;
    if (b < nbin) {
        int e = b * 256 + threadIdx.x;
        if (e < E) {
            int row = ei[e], col = ei[E + e];
            int pos = atomicAdd(&cursor[row], 1) + pref[row >> 10];
            bins[pos] = col;
        }
    } else {
        int i = (b - nbin) * 256 + threadIdx.x;
        if (i < N) offsets[i] += pref[i >> 10];
        else if (i == N) offsets[i] = E;
    }
}

// ---------- fused aggregate + MFMA transform (6x-verified geometry) ----------
// block = 32 nodes, 256 threads = 4 waves.
// Phase A: wave w aggregates local nodes m = w*8..w*8+7 (64 lanes span the
//   node's 512 elems, lane*8), fp32 acc, RNE->bf16, swizzled LDS write:
//   byte = m*1024 + ch*256 + ((slot*16) ^ ((m&15)<<4)); read uses same XOR.
//   Gather 8-deep (8 independent 16B loads in flight), then 4/1.
// Phase B: wave = channel c (0=scalar Ws, 1..3 vector Wv), mfma 32x32x16.
//   D[32x128] = Xroot[32x128]@Wroot^T + Agg[32x128]@Wrel^T (+bias c==0)
//   A-frag: A[m=lane&31][k=(lane>>5)*8+j]; B-frag: W[o=lane&31][k=...].
//   C/D: col=lane&31, row=(reg&3)+8*(reg>>2)+4*(lane>>5)  [measured m74/m101].
// Epilogue: NT stores; each instruction writes two full 128 B lines.
template<int XBF>
__global__ __launch_bounds__(256) void fused_agg_mfma(
    const float* __restrict__ x, const short* __restrict__ xbf,
    const int* __restrict__ offsets, const int* __restrict__ bins,
    float* __restrict__ out, const short* __restrict__ wbf,
    const float* __restrict__ b_s, int Nn)
{
    __shared__ short atile[32 * 512];   // 32 KB swizzled bf16 [m][ch][k]
    const int tid  = threadIdx.x;
    const int wid  = tid >> 6;
    const int lane = tid & 63;
    const int n0   = blockIdx.x * 32;

    // ---- Phase A: aggregate 8 nodes per wave into LDS ----
    const int cl   = lane >> 4;         // channel covered by this lane
    const int slot = lane & 15;         // 16B slot within the channel row
    #pragma unroll 1
    for (int i = 0; i < 8; i++) {
        const int m = wid * 8 + i;
        const int n = n0 + m;
        float acc[8] = {0, 0, 0, 0, 0, 0, 0, 0};
        if (n < Nn) {
            const int beg = offsets[n], end = offsets[n + 1];
            int e = beg;
            if (XBF) {
                for (; e + 8 <= end; e += 8) {
                    int cc[8];
                    #pragma unroll
                    for (int q = 0; q < 8; q++) cc[q] = bins[e + q];
                    bfrag v[8];
                    #pragma unroll
                    for (int q = 0; q < 8; q++)
                        v[q] = *(const bfrag*)(xbf + (size_t)cc[q] * 512 + lane * 8);
                    #pragma unroll
                    for (int j = 0; j < 8; j++)
                        acc[j] += ((bf2f(v[0][j]) + bf2f(v[1][j])) +
                                   (bf2f(v[2][j]) + bf2f(v[3][j]))) +
                                  ((bf2f(v[4][j]) + bf2f(v[5][j])) +
                                   (bf2f(v[6][j]) + bf2f(v[7][j])));
                }
                for (; e + 4 <= end; e += 4) {
                    int c4[4];
                    #pragma unroll
                    for (int q = 0; q < 4; q++) c4[q] = bins[e + q];
                    bfrag v[4];
                    #pragma unroll
                    for (int q = 0; q < 4; q++)
                        v[q] = *(const bfrag*)(xbf + (size_t)c4[q] * 512 + lane * 8);
                    #pragma unroll
                    for (int j = 0; j < 8; j++)
                        acc[j] += (bf2f(v[0][j]) + bf2f(v[1][j])) +
                                  (bf2f(v[2][j]) + bf2f(v[3][j]));
                }
                for (; e < end; e++) {
                    int cc1 = bins[e];
                    bfrag v = *(const bfrag*)(xbf + (size_t)cc1 * 512 + lane * 8);
                    #pragma unroll
                    for (int j = 0; j < 8; j++) acc[j] += bf2f(v[j]);
                }
            } else {
                for (; e < end; e++) {
                    int cc1 = bins[e];
                    float4 l = *(const float4*)(x + (size_t)cc1 * 512 + lane * 8);
                    float4 h = *(const float4*)(x + (size_t)cc1 * 512 + lane * 8 + 4);
                    acc[0] += l.x; acc[1] += l.y; acc[2] += l.z; acc[3] += l.w;
                    acc[4] += h.x; acc[5] += h.y; acc[6] += h.z; acc[7] += h.w;
                }
            }
        }
        const int boff = m * 1024 + cl * 256 + ((slot * 16) ^ ((m & 15) << 4));
        *(bfrag*)((char*)atile + boff) =
            pack8(make_float4(acc[0], acc[1], acc[2], acc[3]),
                  make_float4(acc[4], acc[5], acc[6], acc[7]));
    }

    // ---- preload root-x fragments (independent of LDS; hides under barrier) ----
    const int c   = wid;                 // wave = channel
    const int l31 = lane & 31;
    const int kg  = lane >> 5;           // k-group 0/1
    int mA = n0 + l31; if (mA >= Nn) mA = Nn - 1;   // clamped A-row node
    const size_t arow = ((size_t)mA * 4 + c) * 128;
    bfrag a0[8];
    #pragma unroll
    for (int ks = 0; ks < 8; ks++) {
        const int k0 = ks * 16 + kg * 8;
        if (XBF) {
            a0[ks] = *(const bfrag*)(xbf + arow + k0);
        } else {
            float4 lo = *(const float4*)(x + arow + k0);
            float4 hi = *(const float4*)(x + arow + k0 + 4);
            a0[ks] = pack8(lo, hi);
        }
    }

    __syncthreads();

    // ---- Phase B: MFMA ----
    const short* wroot = wbf + ((c == 0) ? 0 : 2) * 16384;
    const short* wrel  = wbf + ((c == 0) ? 1 : 3) * 16384;

    cfrag acc4[4];
    #pragma unroll
    for (int t = 0; t < 4; t++)
        #pragma unroll
        for (int r = 0; r < 16; r++) acc4[t][r] = 0.f;

    __builtin_amdgcn_s_setprio(1);
    #pragma unroll
    for (int ks = 0; ks < 8; ks++) {
        const int k0 = ks * 16 + kg * 8;
        // agg A-frag from swizzled LDS (node = l31, channel = c)
        const int rboff = l31 * 1024 + c * 256 + ((k0 * 2) ^ ((l31 & 15) << 4));
        bfrag a1 = *(const bfrag*)((const char*)atile + rboff);
        #pragma unroll
        for (int t = 0; t < 4; t++) {
            bfrag b0 = *(const bfrag*)(wroot + (size_t)(t * 32 + l31) * 128 + k0);
            acc4[t] = __builtin_amdgcn_mfma_f32_32x32x16_bf16(a0[ks], b0, acc4[t], 0, 0, 0);
            bfrag b1 = *(const bfrag*)(wrel + (size_t)(t * 32 + l31) * 128 + k0);
            acc4[t] = __builtin_amdgcn_mfma_f32_32x32x16_bf16(a1, b1, acc4[t], 0, 0, 0);
        }
    }
    __builtin_amdgcn_s_setprio(0);

    float bv[4] = {0.f, 0.f, 0.f, 0.f};
    if (c == 0) {
        #pragma unroll
        for (int t = 0; t < 4; t++) bv[t] = b_s[t * 32 + l31];
    }

    #pragma unroll
    for (int t = 0; t < 4; t++) {
        #pragma unroll
        for (int r = 0; r < 16; r++) {
            int row = (r & 3) + 8 * (r >> 2) + 4 * kg;
            int node = n0 + row;
            if (node < Nn)
                __builtin_nontemporal_store(
                    acc4[t][r] + bv[t],
                    out + ((size_t)node * 4 + c) * 128 + t * 32 + l31);
        }
    }
}

extern "C" void kernel_launch(void* const* d_in, const int* in_sizes, int n_in,
                              void* d_out, int out_size, void* d_ws, size_t ws_size,
                              hipStream_t stream) {
    const float* x        = (const float*)d_in[0];
    const int*   ei       = (const int*)d_in[1];
    const float* W_s_rel  = (const float*)d_in[2];
    const float* W_s_root = (const float*)d_in[3];
    const float* b_s_root = (const float*)d_in[4];
    const float* W_v_rel  = (const float*)d_in[5];
    const float* W_v_root = (const float*)d_in[6];
    float* out = (float*)d_out;

    int N = in_sizes[0] / 512;   // 50000
    int E = in_sizes[1] / 2;     // 500000

    // ws layout: wbf[65536 shorts] | (xbf[N*512 shorts] if it fits) | ints:
    //   counts[N] offsets[N+1] cursor[N] bins[E] blocksums[64]
    size_t ints_bytes = ((size_t)(3 * N + 1) + E + 64) * sizeof(int);
    size_t wbf_bytes  = 65536 * sizeof(short);
    size_t xbf_bytes  = (size_t)N * 512 * sizeof(short);
    bool use_bf = (ws_size >= wbf_bytes + xbf_bytes + ints_bytes);

    short* wbf = (short*)d_ws;
    short* xbf = wbf + 65536;
    int* counts = use_bf ? (int*)(xbf + (size_t)N * 512) : (int*)xbf;
    int* offsets   = counts + N;
    int* cursor    = offsets + N + 1;
    int* bins      = cursor + N;
    int* blocksums = bins + E;

    int nb = (N + 1023) / 1024;                 // 49 (<= 64 for N <= 64K)
    long long total8 = (long long)N * 64;       // N*512/8
    int nconv = use_bf ? (int)((total8 + 255) / 256) : 0;
    int nbin  = (E + 255) / 256;                // 1954
    int nfix  = (N + 1 + 255) / 256;            // 196

    hipMemsetAsync(counts, 0, (size_t)N * sizeof(int), stream);
    prep_kernel<<<nconv + 32 + nbin, 256, 0, stream>>>(
        x, xbf, total8, W_s_root, W_s_rel, W_v_root, W_v_rel, wbf,
        ei, counts, E, nconv);
    scan_local_kernel<<<nb, 1024, 0, stream>>>(counts, offsets, cursor, blocksums, N);
    binfix_kernel<<<nbin + nfix, 256, 0, stream>>>(
        ei, cursor, bins, E, offsets, blocksums, nb, N, nbin);

    if (use_bf) {
        fused_agg_mfma<1><<<(N + 31) / 32, 256, 0, stream>>>(
            x, xbf, offsets, bins, out, wbf, b_s_root, N);
    } else {
        fused_agg_mfma<0><<<(N + 31) / 32, 256, 0, stream>>>(
            x, nullptr, offsets, bins, out, wbf, b_s_root, N);
    }
}